// Round 4
// baseline (1092.963 us; speedup 1.0000x reference)
//
#include <hip/hip_runtime.h>

typedef float f32x4 __attribute__((ext_vector_type(4)));
typedef __bf16 bf16x8 __attribute__((ext_vector_type(8)));

__device__ inline unsigned short f2bf(float f) {
  unsigned int u = __float_as_uint(f);
  u += 0x7fffu + ((u >> 16) & 1u);
  return (unsigned short)(u >> 16);
}
__device__ inline float bf2f(unsigned short b) {
  return __uint_as_float(((unsigned int)b) << 16);
}

__device__ inline f32x4 mfma_bf16(bf16x8 a, bf16x8 b, f32x4 c) {
  return __builtin_amdgcn_mfma_f32_16x16x32_bf16(a, b, c, 0, 0, 0);
}

// ---------------- f32 -> bf16 elementwise convert (x) ----------------
__global__ __launch_bounds__(256) void k_cvt_bf16(const float* __restrict__ src,
                                                  unsigned short* __restrict__ dst,
                                                  int n4) {
  int i = blockIdx.x * 256 + threadIdx.x;
  if (i >= n4) return;
  float4 v = ((const float4*)src)[i];
  ushort4 o;
  o.x = f2bf(v.x); o.y = f2bf(v.y); o.z = f2bf(v.z); o.w = f2bf(v.w);
  ((ushort4*)dst)[i] = o;
}

// ---------------- f32 [K][N] -> bf16 [N][K] transpose-convert ----------------
__global__ __launch_bounds__(256) void k_transpose_cvt(const float* __restrict__ src,
                                                       unsigned short* __restrict__ dst,
                                                       int K, int N) {
  __shared__ float tile[32][33];
  int bx = blockIdx.x * 32;  // N direction
  int by = blockIdx.y * 32;  // K direction
  int tx = threadIdx.x, ty = threadIdx.y;
#pragma unroll
  for (int i = 0; i < 32; i += 8)
    tile[ty + i][tx] = src[(long)(by + ty + i) * N + bx + tx];
  __syncthreads();
#pragma unroll
  for (int i = 0; i < 32; i += 8)
    dst[(long)(bx + ty + i) * K + by + tx] = f2bf(tile[tx][ty + i]);
}

// ---------------- f32 [K][N] -> bf16 hi/lo [N][K] transpose-split ----------------
__global__ __launch_bounds__(256) void k_transpose_split(const float* __restrict__ src,
                                                         unsigned short* __restrict__ dh,
                                                         unsigned short* __restrict__ dl,
                                                         int K, int N) {
  __shared__ float tile[32][33];
  int bx = blockIdx.x * 32;
  int by = blockIdx.y * 32;
  int tx = threadIdx.x, ty = threadIdx.y;
#pragma unroll
  for (int i = 0; i < 32; i += 8)
    tile[ty + i][tx] = src[(long)(by + ty + i) * N + bx + tx];
  __syncthreads();
#pragma unroll
  for (int i = 0; i < 32; i += 8) {
    float v = tile[tx][ty + i];
    unsigned short h = f2bf(v);
    long idx = (long)(bx + ty + i) * K + by + tx;
    dh[idx] = h;
    dl[idx] = f2bf(v - bf2f(h));
  }
}

// ---------------- bf16 GEMM: C[M,N] = A[M,K] * B^T[N,K] ----------------
// 128x128 tile, BK=32, 256 threads (4 waves in 2x2), mfma 16x16x32 bf16.
template <int OUTF32>
__global__ __launch_bounds__(256) void k_gemm_bt(const unsigned short* __restrict__ A,
                                                 const unsigned short* __restrict__ B,
                                                 void* __restrict__ Cout,
                                                 int M, int N, int K) {
  __shared__ __align__(16) unsigned short As[128 * 32];
  __shared__ __align__(16) unsigned short Bs[128 * 32];
  const int tid = threadIdx.x;
  const int l = tid & 63;
  const int w = tid >> 6;
  const int lr = l & 15, lq = l >> 4;
  const int wr = w >> 1, wc = w & 1;
  const long row0 = (long)blockIdx.x * 128;
  const long col0 = (long)blockIdx.y * 128;

  f32x4 acc[4][4] = {};

  const int ar = tid >> 2;       // staging row 0..63 (and +64)
  const int ak = (tid & 3) * 8;  // staging k-offset (elements)
  const unsigned short* Ap = A + (row0 + ar) * (long)K + ak;
  const unsigned short* Bp = B + (col0 + ar) * (long)K + ak;
  const long rstep = 64 * (long)K;

  for (int kt = 0; kt < K; kt += 32) {
    uint4 a0 = *(const uint4*)(Ap + kt);
    uint4 a1 = *(const uint4*)(Ap + rstep + kt);
    uint4 b0 = *(const uint4*)(Bp + kt);
    uint4 b1 = *(const uint4*)(Bp + rstep + kt);
    __syncthreads();
    *(uint4*)((char*)As + tid * 16) = a0;
    *(uint4*)((char*)As + tid * 16 + 4096) = a1;
    *(uint4*)((char*)Bs + tid * 16) = b0;
    *(uint4*)((char*)Bs + tid * 16 + 4096) = b1;
    __syncthreads();
    bf16x8 af[4], bfr[4];
#pragma unroll
    for (int mi = 0; mi < 4; mi++)
      af[mi] = *(const bf16x8*)((const char*)As + (64 * wr + 16 * mi + lr) * 64 + lq * 16);
#pragma unroll
    for (int ni = 0; ni < 4; ni++)
      bfr[ni] = *(const bf16x8*)((const char*)Bs + (64 * wc + 16 * ni + lr) * 64 + lq * 16);
#pragma unroll
    for (int mi = 0; mi < 4; mi++)
#pragma unroll
      for (int ni = 0; ni < 4; ni++)
        acc[mi][ni] = mfma_bf16(af[mi], bfr[ni], acc[mi][ni]);
  }

#pragma unroll
  for (int mi = 0; mi < 4; mi++) {
#pragma unroll
    for (int ni = 0; ni < 4; ni++) {
#pragma unroll
      for (int r = 0; r < 4; r++) {
        long row = row0 + 64 * wr + 16 * mi + 4 * lq + r;
        long col = col0 + 64 * wc + 16 * ni + lr;
        float v = acc[mi][ni][r];
        if (OUTF32)
          ((float*)Cout)[row * N + col] = v;
        else
          ((unsigned short*)Cout)[row * N + col] = f2bf(v);
      }
    }
  }
}

// ---------------- split-bf16 GEMM (f32-accurate): C = A_f32 * B^T(hi+lo) ----------------
// 3-term: hi*hi + hi*lo + lo*hi. A read as f32 from global, split in-kernel.
__global__ __launch_bounds__(256) void k_gemm_kv(const float* __restrict__ A,
                                                 const unsigned short* __restrict__ Bh,
                                                 const unsigned short* __restrict__ Bl,
                                                 float* __restrict__ C,
                                                 int M, int N, int K) {
  __shared__ __align__(16) unsigned short Ash[128 * 32];
  __shared__ __align__(16) unsigned short Asl[128 * 32];
  __shared__ __align__(16) unsigned short Bsh[128 * 32];
  __shared__ __align__(16) unsigned short Bsl[128 * 32];
  const int tid = threadIdx.x;
  const int l = tid & 63;
  const int w = tid >> 6;
  const int lr = l & 15, lq = l >> 4;
  const int wr = w >> 1, wc = w & 1;
  const long row0 = (long)blockIdx.x * 128;
  const long col0 = (long)blockIdx.y * 128;

  f32x4 acc[4][4] = {};

  const int arow = tid >> 1;        // 0..127
  const int acol = (tid & 1) * 16;  // f32 element offset within 32
  const float* Ap = A + (row0 + arow) * (long)K + acol;
  const int brow = tid >> 2;        // 0..63 (and +64)
  const int bcol = (tid & 3) * 8;
  const unsigned short* Bph = Bh + (col0 + brow) * (long)K + bcol;
  const unsigned short* Bpl = Bl + (col0 + brow) * (long)K + bcol;
  const long brstep = 64 * (long)K;

  for (int kt = 0; kt < K; kt += 32) {
    float av[16];
    *(float4*)(av + 0)  = *(const float4*)(Ap + kt + 0);
    *(float4*)(av + 4)  = *(const float4*)(Ap + kt + 4);
    *(float4*)(av + 8)  = *(const float4*)(Ap + kt + 8);
    *(float4*)(av + 12) = *(const float4*)(Ap + kt + 12);
    uint4 bh0 = *(const uint4*)(Bph + kt);
    uint4 bh1 = *(const uint4*)(Bph + brstep + kt);
    uint4 bl0 = *(const uint4*)(Bpl + kt);
    uint4 bl1 = *(const uint4*)(Bpl + brstep + kt);
    unsigned short hb[16], lb[16];
#pragma unroll
    for (int i = 0; i < 16; i++) {
      unsigned short h = f2bf(av[i]);
      hb[i] = h;
      lb[i] = f2bf(av[i] - bf2f(h));
    }
    __syncthreads();
    *(uint4*)((char*)Ash + arow * 64 + acol * 2)      = *(uint4*)(hb + 0);
    *(uint4*)((char*)Ash + arow * 64 + acol * 2 + 16) = *(uint4*)(hb + 8);
    *(uint4*)((char*)Asl + arow * 64 + acol * 2)      = *(uint4*)(lb + 0);
    *(uint4*)((char*)Asl + arow * 64 + acol * 2 + 16) = *(uint4*)(lb + 8);
    *(uint4*)((char*)Bsh + tid * 16)        = bh0;
    *(uint4*)((char*)Bsh + tid * 16 + 4096) = bh1;
    *(uint4*)((char*)Bsl + tid * 16)        = bl0;
    *(uint4*)((char*)Bsl + tid * 16 + 4096) = bl1;
    __syncthreads();
    bf16x8 ah[4], alo[4], bhf[4], blf[4];
#pragma unroll
    for (int mi = 0; mi < 4; mi++) {
      const int off = (64 * wr + 16 * mi + lr) * 64 + lq * 16;
      ah[mi]  = *(const bf16x8*)((const char*)Ash + off);
      alo[mi] = *(const bf16x8*)((const char*)Asl + off);
    }
#pragma unroll
    for (int ni = 0; ni < 4; ni++) {
      const int off = (64 * wc + 16 * ni + lr) * 64 + lq * 16;
      bhf[ni] = *(const bf16x8*)((const char*)Bsh + off);
      blf[ni] = *(const bf16x8*)((const char*)Bsl + off);
    }
#pragma unroll
    for (int mi = 0; mi < 4; mi++)
#pragma unroll
      for (int ni = 0; ni < 4; ni++) {
        acc[mi][ni] = mfma_bf16(ah[mi], bhf[ni], acc[mi][ni]);
        acc[mi][ni] = mfma_bf16(ah[mi], blf[ni], acc[mi][ni]);
        acc[mi][ni] = mfma_bf16(alo[mi], bhf[ni], acc[mi][ni]);
      }
  }

#pragma unroll
  for (int mi = 0; mi < 4; mi++)
#pragma unroll
    for (int ni = 0; ni < 4; ni++)
#pragma unroll
      for (int r = 0; r < 4; r++) {
        long row = row0 + 64 * wr + 16 * mi + 4 * lq + r;
        long col = col0 + 64 * wc + 16 * ni + lr;
        C[row * N + col] = acc[mi][ni][r];
      }
}

// ---------------- pointwise Q: RoPE + RMSNorm, bf16 in/out ----------------
// qkv_q: [8192][2048] bf16 -> qh: [16][8192][128] bf16
__global__ __launch_bounds__(256) void k_pointwise_q(const unsigned short* __restrict__ qkv_q,
                                                     const float* __restrict__ cosp,
                                                     const float* __restrict__ sinp,
                                                     unsigned short* __restrict__ qh) {
  const int tid = threadIdx.x;
  const int w = tid >> 6, l = tid & 63;
  const int wid = blockIdx.x * 4 + w;
  const int t = wid >> 4;
  const int hq = wid & 15;
  const unsigned short* row = qkv_q + (long)t * 2048 + hq * 128;
  float x1 = bf2f(row[l]);
  float x2 = bf2f(row[64 + l]);
  float c = cosp[t * 64 + l];
  float s = sinp[t * 64 + l];
  float r1 = x1 * c + x2 * s;
  float r2 = x2 * c - x1 * s;
  float ss = r1 * r1 + r2 * r2;
#pragma unroll
  for (int d = 1; d < 64; d <<= 1) ss += __shfl_xor(ss, d);
  float sc = 1.0f / sqrtf(ss * (1.0f / 128.0f) + 1.1920929e-07f);
  unsigned short* dst = qh + ((long)hq * 8192 + t) * 128;
  dst[l] = f2bf(r1 * sc);
  dst[64 + l] = f2bf(r2 * sc);
}

// ---------------- pointwise KV: RoPE + RMS + quant (K), quant (V), f32 in ----------------
// kv: [8192][1024] f32 (k cols 0..511, v cols 512..1023)
// kh: [4][8192][128] bf16, vt: [4][128][8192] bf16
__global__ __launch_bounds__(256) void k_pointwise_kv(const float* __restrict__ kv,
                                                      const float* __restrict__ cosp,
                                                      const float* __restrict__ sinp,
                                                      unsigned short* __restrict__ kh,
                                                      unsigned short* __restrict__ vt) {
  const int tid = threadIdx.x;
  const int w = tid >> 6, l = tid & 63;
  const int wid = blockIdx.x * 4 + w;
  const int t = wid >> 3;
  const int job = wid & 7;
  if (job < 4) {
    const float* rowp = kv + (long)t * 1024 + job * 128;
    float x1 = rowp[l];
    float x2 = rowp[64 + l];
    float c = cosp[t * 64 + l];
    float s = sinp[t * 64 + l];
    float r1 = x1 * c + x2 * s;
    float r2 = x2 * c - x1 * s;
    float ss = r1 * r1 + r2 * r2;
#pragma unroll
    for (int d = 1; d < 64; d <<= 1) ss += __shfl_xor(ss, d);
    float sc = 1.0f / sqrtf(ss * (1.0f / 128.0f) + 1.1920929e-07f);
    r1 *= sc;
    r2 *= sc;
    float am = fmaxf(fabsf(r1), fabsf(r2));
#pragma unroll
    for (int d = 1; d < 64; d <<= 1) am = fmaxf(am, __shfl_xor(am, d));
    float sq = fmaxf(am * (1.0f / 3.0f), 1e-8f);
    r1 = fminf(fmaxf(rintf(r1 / sq), -3.0f), 3.0f) * sq;
    r2 = fminf(fmaxf(rintf(r2 / sq), -3.0f), 3.0f) * sq;
    unsigned short* dst = kh + ((long)job * 8192 + t) * 128;
    dst[l] = f2bf(r1);
    dst[64 + l] = f2bf(r2);
  } else {
    const int hv = job - 4;
    const float* rowp = kv + (long)t * 1024 + 512 + hv * 128;
    float v1 = rowp[l];
    float v2 = rowp[64 + l];
    float am = fmaxf(fabsf(v1), fabsf(v2));
#pragma unroll
    for (int d = 1; d < 64; d <<= 1) am = fmaxf(am, __shfl_xor(am, d));
    float sq = fmaxf(am * (1.0f / 3.0f), 1e-8f);
    v1 = fminf(fmaxf(rintf(v1 / sq), -3.0f), 3.0f) * sq;
    v2 = fminf(fmaxf(rintf(v2 / sq), -3.0f), 3.0f) * sq;
    vt[((long)(hv * 128 + l)) * 8192 + t] = f2bf(v1);
    vt[((long)(hv * 128 + 64 + l)) * 8192 + t] = f2bf(v2);
  }
}

// ---------------- sliding-window flash attention ----------------
// grid = (64 q-tiles, 16 heads); block = 256 (4 independent waves x 32 q-rows)
__global__ __launch_bounds__(256) void k_attn(const unsigned short* __restrict__ qh,
                                              const unsigned short* __restrict__ kh,
                                              const unsigned short* __restrict__ vt,
                                              unsigned short* __restrict__ y) {
  const int qi = blockIdx.x;
  const int h = blockIdx.y;
  const int kvh = h >> 2;
  const int tid = threadIdx.x;
  const int w = tid >> 6, l = tid & 63;
  const int lr = l & 15, lq = l >> 4;
  const int t0 = qi * 128;
  const int qrow0 = t0 + 32 * w;

  __shared__ __align__(16) unsigned short Pl[4][32 * 136];
  unsigned short* pw = &Pl[w][0];

  const unsigned short* qbase = qh + (long)h * 8192 * 128;
  const unsigned short* kbase = kh + (long)kvh * 8192 * 128;
  const unsigned short* vbase = vt + (long)kvh * 128 * 8192;

  bf16x8 aq[2][4];
#pragma unroll
  for (int mi = 0; mi < 2; mi++)
#pragma unroll
    for (int kk = 0; kk < 4; kk++)
      aq[mi][kk] = *(const bf16x8*)(qbase + (long)(qrow0 + 16 * mi + lr) * 128 + 32 * kk + 8 * lq);

  f32x4 o[2][8] = {};
  float mrow[2][4], lrow[2][4];
#pragma unroll
  for (int mi = 0; mi < 2; mi++)
#pragma unroll
    for (int r = 0; r < 4; r++) {
      mrow[mi][r] = -1e30f;
      lrow[mi][r] = 0.f;
    }

  const int ktlo = (qi >= 8) ? (qi - 8) : 0;
  for (int kt = ktlo; kt <= qi; ++kt) {
    const int key0 = kt * 128;
    f32x4 s[2][8] = {};
#pragma unroll
    for (int kk = 0; kk < 4; kk++) {
#pragma unroll
      for (int ni = 0; ni < 8; ni++) {
        bf16x8 bk = *(const bf16x8*)(kbase + (long)(key0 + 16 * ni + lr) * 128 + 32 * kk + 8 * lq);
        s[0][ni] = mfma_bf16(aq[0][kk], bk, s[0][ni]);
        s[1][ni] = mfma_bf16(aq[1][kk], bk, s[1][ni]);
      }
    }
    const float scale = 0.08838834764831845f;
#pragma unroll
    for (int mi = 0; mi < 2; mi++) {
#pragma unroll
      for (int ni = 0; ni < 8; ni++) {
        const int key = key0 + 16 * ni + lr;
#pragma unroll
        for (int r = 0; r < 4; r++) {
          const int trow = qrow0 + 16 * mi + 4 * lq + r;
          float v = s[mi][ni][r] * scale;
          bool valid = (key <= trow) && (key + 1024 > trow);
          s[mi][ni][r] = valid ? v : -1e30f;
        }
      }
    }
    // online softmax (rows live on 16-lane groups: cols = lr)
#pragma unroll
    for (int mi = 0; mi < 2; mi++) {
#pragma unroll
      for (int r = 0; r < 4; r++) {
        float rm = s[mi][0][r];
#pragma unroll
        for (int ni = 1; ni < 8; ni++) rm = fmaxf(rm, s[mi][ni][r]);
#pragma unroll
        for (int d = 1; d < 16; d <<= 1) rm = fmaxf(rm, __shfl_xor(rm, d));
        float mold = mrow[mi][r];
        float mnew = fmaxf(mold, rm);
        float alpha = expf(mold - mnew);
        mrow[mi][r] = mnew;
        float rsum = 0.f;
#pragma unroll
        for (int ni = 0; ni < 8; ni++) {
          float p = expf(s[mi][ni][r] - mnew);
          s[mi][ni][r] = p;
          rsum += p;
        }
#pragma unroll
        for (int d = 1; d < 16; d <<= 1) rsum += __shfl_xor(rsum, d);
        lrow[mi][r] = lrow[mi][r] * alpha + rsum;
#pragma unroll
        for (int ni = 0; ni < 8; ni++) o[mi][ni][r] *= alpha;
      }
    }
    // P (D-layout) -> LDS, re-read as A-fragments (same wave; lgkmcnt orders)
#pragma unroll
    for (int mi = 0; mi < 2; mi++)
#pragma unroll
      for (int ni = 0; ni < 8; ni++)
#pragma unroll
        for (int r = 0; r < 4; r++)
          pw[(16 * mi + 4 * lq + r) * 136 + 16 * ni + lr] = f2bf(s[mi][ni][r]);
#pragma unroll
    for (int ks = 0; ks < 4; ks++) {
      bf16x8 pa0 = *(const bf16x8*)(pw + lr * 136 + 32 * ks + 8 * lq);
      bf16x8 pa1 = *(const bf16x8*)(pw + (16 + lr) * 136 + 32 * ks + 8 * lq);
#pragma unroll
      for (int ni = 0; ni < 8; ni++) {
        bf16x8 vb = *(const bf16x8*)(vbase + (long)(16 * ni + lr) * 8192 + key0 + 32 * ks + 8 * lq);
        o[0][ni] = mfma_bf16(pa0, vb, o[0][ni]);
        o[1][ni] = mfma_bf16(pa1, vb, o[1][ni]);
      }
    }
  }
  // epilogue: divide by l, write y[t][h*128+d]
#pragma unroll
  for (int mi = 0; mi < 2; mi++) {
#pragma unroll
    for (int r = 0; r < 4; r++) {
      float inv = 1.0f / lrow[mi][r];
      const long trow = qrow0 + 16 * mi + 4 * lq + r;
#pragma unroll
      for (int ni = 0; ni < 8; ni++)
        y[trow * 2048 + h * 128 + 16 * ni + lr] = f2bf(o[mi][ni][r] * inv);
    }
  }
}

extern "C" void kernel_launch(void* const* d_in, const int* in_sizes, int n_in,
                              void* d_out, int out_size, void* d_ws, size_t ws_size,
                              hipStream_t stream) {
  const float* x = (const float*)d_in[0];
  const float* cosp = (const float*)d_in[1];
  const float* sinp = (const float*)d_in[2];
  const float* Wq = (const float*)d_in[3];
  const float* Wk = (const float*)d_in[4];
  const float* Wv = (const float*)d_in[5];
  const float* Wp = (const float*)d_in[6];
  float* out = (float*)d_out;
  char* ws = (char*)d_ws;

  // workspace (96 MB peak, overlapped lifetimes):
  //  [0,        33.5M)  xb (x bf16)        -> qh after Q-GEMM+pointwise_q
  //  [33.5M,    41.9M)  Wtq (Wq^T bf16)    (dead after Q-GEMM)
  //  [41.9M,    50.3M)  Wkv hi|lo          -> kh after KV-GEMM
  //  [50.3M,    58.7M)  Wpt (Wproj^T)      (live to end)
  //  [58.7M,    92.3M)  kv f32             -> qkv_q bf16 -> y bf16
  //  [92.3M,   100.7M)  vt
  unsigned short* xb    = (unsigned short*)(ws);
  unsigned short* Wtq   = (unsigned short*)(ws + 33554432L);
  unsigned short* Wkh   = (unsigned short*)(ws + 41943040L);
  unsigned short* Wkl   = (unsigned short*)(ws + 46137344L);
  unsigned short* Wpt   = (unsigned short*)(ws + 50331648L);
  float*          kv    = (float*)(ws + 58720256L);
  unsigned short* vt    = (unsigned short*)(ws + 92274688L);
  unsigned short* qh    = xb;                                   // over xb
  unsigned short* kh    = (unsigned short*)(ws + 41943040L);    // over Wkh+Wkl
  unsigned short* qkv_q = (unsigned short*)(ws + 58720256L);    // over kv
  unsigned short* y     = qkv_q;                                // over qkv_q

  dim3 tb(32, 8);
  k_cvt_bf16<<<16384, 256, 0, stream>>>(x, xb, 4194304);
  k_transpose_cvt<<<dim3(64, 64), tb, 0, stream>>>(Wq, Wtq, 2048, 2048);
  k_transpose_cvt<<<dim3(64, 64), tb, 0, stream>>>(Wp, Wpt, 2048, 2048);
  k_transpose_split<<<dim3(16, 64), tb, 0, stream>>>(Wk, Wkh, Wkl, 2048, 512);
  k_transpose_split<<<dim3(16, 64), tb, 0, stream>>>(Wv, Wkh + 512L * 2048L, Wkl + 512L * 2048L, 2048, 512);

  k_gemm_kv<<<dim3(64, 8), 256, 0, stream>>>(x, Wkh, Wkl, kv, 8192, 1024, 2048);
  k_pointwise_kv<<<16384, 256, 0, stream>>>(kv, cosp, sinp, kh, vt);
  k_gemm_bt<0><<<dim3(64, 16), 256, 0, stream>>>(xb, Wtq, (void*)qkv_q, 8192, 2048, 2048);
  k_pointwise_q<<<32768, 256, 0, stream>>>(qkv_q, cosp, sinp, qh);
  k_attn<<<dim3(64, 16), 256, 0, stream>>>(qh, kh, vt, y);
  k_gemm_bt<1><<<dim3(64, 16), 256, 0, stream>>>(y, Wpt, (void*)out, 8192, 2048, 2048);
}

// Round 6
// 837.771 us; speedup vs baseline: 1.3046x; 1.3046x over previous
//
#include <hip/hip_runtime.h>

typedef float f32x4 __attribute__((ext_vector_type(4)));
typedef __bf16 bf16x8 __attribute__((ext_vector_type(8)));

__device__ inline unsigned short f2bf(float f) {
  unsigned int u = __float_as_uint(f);
  u += 0x7fffu + ((u >> 16) & 1u);
  return (unsigned short)(u >> 16);
}
__device__ inline float bf2f(unsigned short b) {
  return __uint_as_float(((unsigned int)b) << 16);
}

__device__ inline f32x4 mfma_bf16(bf16x8 a, bf16x8 b, f32x4 c) {
  return __builtin_amdgcn_mfma_f32_16x16x32_bf16(a, b, c, 0, 0, 0);
}

// async global->LDS, 16B per lane. LDS dest must be linear in lane id.
__device__ inline void gload16(const void* g, void* l) {
  __builtin_amdgcn_global_load_lds((const __attribute__((address_space(1))) void*)g,
                                   (__attribute__((address_space(3))) void*)l, 16, 0, 0);
}

// ---------------- f32 -> bf16 elementwise convert (x) ----------------
__global__ __launch_bounds__(256) void k_cvt_bf16(const float* __restrict__ src,
                                                  unsigned short* __restrict__ dst,
                                                  int n4) {
  int i = blockIdx.x * 256 + threadIdx.x;
  if (i >= n4) return;
  float4 v = ((const float4*)src)[i];
  ushort4 o;
  o.x = f2bf(v.x); o.y = f2bf(v.y); o.z = f2bf(v.z); o.w = f2bf(v.w);
  ((ushort4*)dst)[i] = o;
}

// ---------------- f32 [K][N] -> bf16 [N][K] transpose-convert ----------------
__global__ __launch_bounds__(256) void k_transpose_cvt(const float* __restrict__ src,
                                                       unsigned short* __restrict__ dst,
                                                       int K, int N) {
  __shared__ float tile[32][33];
  int bx = blockIdx.x * 32;  // N direction
  int by = blockIdx.y * 32;  // K direction
  int tx = threadIdx.x, ty = threadIdx.y;
#pragma unroll
  for (int i = 0; i < 32; i += 8)
    tile[ty + i][tx] = src[(long)(by + ty + i) * N + bx + tx];
  __syncthreads();
#pragma unroll
  for (int i = 0; i < 32; i += 8)
    dst[(long)(bx + ty + i) * K + by + tx] = f2bf(tile[tx][ty + i]);
}

// ---------------- f32 [K][N] -> bf16 hi/lo [N][K] transpose-split ----------------
__global__ __launch_bounds__(256) void k_transpose_split(const float* __restrict__ src,
                                                         unsigned short* __restrict__ dh,
                                                         unsigned short* __restrict__ dl,
                                                         int K, int N) {
  __shared__ float tile[32][33];
  int bx = blockIdx.x * 32;
  int by = blockIdx.y * 32;
  int tx = threadIdx.x, ty = threadIdx.y;
#pragma unroll
  for (int i = 0; i < 32; i += 8)
    tile[ty + i][tx] = src[(long)(by + ty + i) * N + bx + tx];
  __syncthreads();
#pragma unroll
  for (int i = 0; i < 32; i += 8) {
    float v = tile[tx][ty + i];
    unsigned short h = f2bf(v);
    long idx = (long)(bx + ty + i) * K + by + tx;
    dh[idx] = h;
    dl[idx] = f2bf(v - bf2f(h));
  }
}

// ---------------- bf16 GEMM: C[M,N] = A[M,K] * B^T[N,K] ----------------
// 128x128 tile, BK=32, 256 threads, global_load_lds staging (m97 pattern).
template <int OUTF32>
__global__ __launch_bounds__(256) void k_gemm_bt(const unsigned short* __restrict__ A,
                                                 const unsigned short* __restrict__ B,
                                                 void* __restrict__ Cout,
                                                 int M, int N, int K) {
  __shared__ __align__(16) unsigned short As[128 * 32];
  __shared__ __align__(16) unsigned short Bs[128 * 32];
  const int tid = threadIdx.x;
  const int l = tid & 63;
  const int w = tid >> 6;
  const int lr = l & 15, lq = l >> 4;
  const int wr = w >> 1, wc = w & 1;
  const long row0 = (long)blockIdx.x * 128;
  const long col0 = (long)blockIdx.y * 128;

  f32x4 acc[4][4] = {};

  const int ar = tid >> 2;       // staging row 0..63 (and +64)
  const int ak = (tid & 3) * 8;  // staging k-offset (elements)
  const unsigned short* Ap = A + (row0 + ar) * (long)K + ak;
  const unsigned short* Bp = B + (col0 + ar) * (long)K + ak;
  const long rstep = 64 * (long)K;
  char* AsL = (char*)As + tid * 16;
  char* BsL = (char*)Bs + tid * 16;

  for (int kt = 0; kt < K; kt += 32) {
    __syncthreads();  // all waves done reading LDS from prev iter
    gload16(Ap + kt, AsL);
    gload16(Ap + rstep + kt, AsL + 4096);
    gload16(Bp + kt, BsL);
    gload16(Bp + rstep + kt, BsL + 4096);
    __syncthreads();  // drains vmcnt: tiles landed
    bf16x8 af[4], bfr[4];
#pragma unroll
    for (int mi = 0; mi < 4; mi++)
      af[mi] = *(const bf16x8*)((const char*)As + (64 * wr + 16 * mi + lr) * 64 + lq * 16);
#pragma unroll
    for (int ni = 0; ni < 4; ni++)
      bfr[ni] = *(const bf16x8*)((const char*)Bs + (64 * wc + 16 * ni + lr) * 64 + lq * 16);
#pragma unroll
    for (int mi = 0; mi < 4; mi++)
#pragma unroll
      for (int ni = 0; ni < 4; ni++)
        acc[mi][ni] = mfma_bf16(af[mi], bfr[ni], acc[mi][ni]);
  }

#pragma unroll
  for (int mi = 0; mi < 4; mi++) {
#pragma unroll
    for (int ni = 0; ni < 4; ni++) {
#pragma unroll
      for (int r = 0; r < 4; r++) {
        long row = row0 + 64 * wr + 16 * mi + 4 * lq + r;
        long col = col0 + 64 * wc + 16 * ni + lr;
        float v = acc[mi][ni][r];
        if (OUTF32)
          ((float*)Cout)[row * N + col] = v;
        else
          ((unsigned short*)Cout)[row * N + col] = f2bf(v);
      }
    }
  }
}

// ---------------- split-bf16 GEMM (f32-accurate): C = A_f32 * B^T(hi+lo) ----------------
__global__ __launch_bounds__(256) void k_gemm_kv(const float* __restrict__ A,
                                                 const unsigned short* __restrict__ Bh,
                                                 const unsigned short* __restrict__ Bl,
                                                 float* __restrict__ C,
                                                 int M, int N, int K) {
  __shared__ __align__(16) unsigned short Ash[128 * 32];
  __shared__ __align__(16) unsigned short Asl[128 * 32];
  __shared__ __align__(16) unsigned short Bsh[128 * 32];
  __shared__ __align__(16) unsigned short Bsl[128 * 32];
  const int tid = threadIdx.x;
  const int l = tid & 63;
  const int w = tid >> 6;
  const int lr = l & 15, lq = l >> 4;
  const int wr = w >> 1, wc = w & 1;
  const long row0 = (long)blockIdx.x * 128;
  const long col0 = (long)blockIdx.y * 128;

  f32x4 acc[4][4] = {};

  const int arow = tid >> 1;        // 0..127
  const int acol = (tid & 1) * 16;  // f32 element offset within 32
  const float* Ap = A + (row0 + arow) * (long)K + acol;
  const int brow = tid >> 2;
  const int bcol = (tid & 3) * 8;
  const unsigned short* Bph = Bh + (col0 + brow) * (long)K + bcol;
  const unsigned short* Bpl = Bl + (col0 + brow) * (long)K + bcol;
  const long brstep = 64 * (long)K;
  char* BshL = (char*)Bsh + tid * 16;
  char* BslL = (char*)Bsl + tid * 16;

  for (int kt = 0; kt < K; kt += 32) {
    float av[16];
    *(float4*)(av + 0)  = *(const float4*)(Ap + kt + 0);
    *(float4*)(av + 4)  = *(const float4*)(Ap + kt + 4);
    *(float4*)(av + 8)  = *(const float4*)(Ap + kt + 8);
    *(float4*)(av + 12) = *(const float4*)(Ap + kt + 12);
    unsigned short hb[16], lb[16];
#pragma unroll
    for (int i = 0; i < 16; i++) {
      unsigned short h = f2bf(av[i]);
      hb[i] = h;
      lb[i] = f2bf(av[i] - bf2f(h));
    }
    __syncthreads();
    *(uint4*)((char*)Ash + arow * 64 + acol * 2)      = *(uint4*)(hb + 0);
    *(uint4*)((char*)Ash + arow * 64 + acol * 2 + 16) = *(uint4*)(hb + 8);
    *(uint4*)((char*)Asl + arow * 64 + acol * 2)      = *(uint4*)(lb + 0);
    *(uint4*)((char*)Asl + arow * 64 + acol * 2 + 16) = *(uint4*)(lb + 8);
    gload16(Bph + kt, BshL);
    gload16(Bph + brstep + kt, BshL + 4096);
    gload16(Bpl + kt, BslL);
    gload16(Bpl + brstep + kt, BslL + 4096);
    __syncthreads();
    bf16x8 ah[4], alo[4], bhf[4], blf[4];
#pragma unroll
    for (int mi = 0; mi < 4; mi++) {
      const int off = (64 * wr + 16 * mi + lr) * 64 + lq * 16;
      ah[mi]  = *(const bf16x8*)((const char*)Ash + off);
      alo[mi] = *(const bf16x8*)((const char*)Asl + off);
    }
#pragma unroll
    for (int ni = 0; ni < 4; ni++) {
      const int off = (64 * wc + 16 * ni + lr) * 64 + lq * 16;
      bhf[ni] = *(const bf16x8*)((const char*)Bsh + off);
      blf[ni] = *(const bf16x8*)((const char*)Bsl + off);
    }
#pragma unroll
    for (int mi = 0; mi < 4; mi++)
#pragma unroll
      for (int ni = 0; ni < 4; ni++) {
        acc[mi][ni] = mfma_bf16(ah[mi], bhf[ni], acc[mi][ni]);
        acc[mi][ni] = mfma_bf16(ah[mi], blf[ni], acc[mi][ni]);
        acc[mi][ni] = mfma_bf16(alo[mi], bhf[ni], acc[mi][ni]);
      }
  }

#pragma unroll
  for (int mi = 0; mi < 4; mi++)
#pragma unroll
    for (int ni = 0; ni < 4; ni++)
#pragma unroll
      for (int r = 0; r < 4; r++) {
        long row = row0 + 64 * wr + 16 * mi + 4 * lq + r;
        long col = col0 + 64 * wc + 16 * ni + lr;
        C[row * N + col] = acc[mi][ni][r];
      }
}

// ---------------- pointwise Q: RoPE + RMSNorm, PRE-SCALED by scale*log2e ----------------
// qkv_q: [8192][2048] bf16 -> qh: [16][8192][128] bf16 (scaled by 0.0883883*1.4426950)
__global__ __launch_bounds__(256) void k_pointwise_q(const unsigned short* __restrict__ qkv_q,
                                                     const float* __restrict__ cosp,
                                                     const float* __restrict__ sinp,
                                                     unsigned short* __restrict__ qh) {
  const int tid = threadIdx.x;
  const int w = tid >> 6, l = tid & 63;
  const int wid = blockIdx.x * 4 + w;
  const int t = wid >> 4;
  const int hq = wid & 15;
  const unsigned short* row = qkv_q + (long)t * 2048 + hq * 128;
  float x1 = bf2f(row[l]);
  float x2 = bf2f(row[64 + l]);
  float c = cosp[t * 64 + l];
  float s = sinp[t * 64 + l];
  float r1 = x1 * c + x2 * s;
  float r2 = x2 * c - x1 * s;
  float ss = r1 * r1 + r2 * r2;
#pragma unroll
  for (int d = 1; d < 64; d <<= 1) ss += __shfl_xor(ss, d);
  const float QS = 0.12751744f;  // (1/sqrt(128)) * log2(e)
  float sc = QS / sqrtf(ss * (1.0f / 128.0f) + 1.1920929e-07f);
  unsigned short* dst = qh + ((long)hq * 8192 + t) * 128;
  dst[l] = f2bf(r1 * sc);
  dst[64 + l] = f2bf(r2 * sc);
}

// ---------------- pointwise KV: RoPE + RMS + quant (K), quant (V), f32 in ----------------
__global__ __launch_bounds__(256) void k_pointwise_kv(const float* __restrict__ kv,
                                                      const float* __restrict__ cosp,
                                                      const float* __restrict__ sinp,
                                                      unsigned short* __restrict__ kh,
                                                      unsigned short* __restrict__ vt) {
  const int tid = threadIdx.x;
  const int w = tid >> 6, l = tid & 63;
  const int wid = blockIdx.x * 4 + w;
  const int t = wid >> 3;
  const int job = wid & 7;
  if (job < 4) {
    const float* rowp = kv + (long)t * 1024 + job * 128;
    float x1 = rowp[l];
    float x2 = rowp[64 + l];
    float c = cosp[t * 64 + l];
    float s = sinp[t * 64 + l];
    float r1 = x1 * c + x2 * s;
    float r2 = x2 * c - x1 * s;
    float ss = r1 * r1 + r2 * r2;
#pragma unroll
    for (int d = 1; d < 64; d <<= 1) ss += __shfl_xor(ss, d);
    float sc = 1.0f / sqrtf(ss * (1.0f / 128.0f) + 1.1920929e-07f);
    r1 *= sc;
    r2 *= sc;
    float am = fmaxf(fabsf(r1), fabsf(r2));
#pragma unroll
    for (int d = 1; d < 64; d <<= 1) am = fmaxf(am, __shfl_xor(am, d));
    float sq = fmaxf(am * (1.0f / 3.0f), 1e-8f);
    r1 = fminf(fmaxf(rintf(r1 / sq), -3.0f), 3.0f) * sq;
    r2 = fminf(fmaxf(rintf(r2 / sq), -3.0f), 3.0f) * sq;
    unsigned short* dst = kh + ((long)job * 8192 + t) * 128;
    dst[l] = f2bf(r1);
    dst[64 + l] = f2bf(r2);
  } else {
    const int hv = job - 4;
    const float* rowp = kv + (long)t * 1024 + 512 + hv * 128;
    float v1 = rowp[l];
    float v2 = rowp[64 + l];
    float am = fmaxf(fabsf(v1), fabsf(v2));
#pragma unroll
    for (int d = 1; d < 64; d <<= 1) am = fmaxf(am, __shfl_xor(am, d));
    float sq = fmaxf(am * (1.0f / 3.0f), 1e-8f);
    v1 = fminf(fmaxf(rintf(v1 / sq), -3.0f), 3.0f) * sq;
    v2 = fminf(fmaxf(rintf(v2 / sq), -3.0f), 3.0f) * sq;
    vt[((long)(hv * 128 + l)) * 8192 + t] = f2bf(v1);
    vt[((long)(hv * 128 + 64 + l)) * 8192 + t] = f2bf(v2);
  }
}

// ---------------- sliding-window flash attention, fixed-max softmax ----------------
// Q pre-scaled by scale*log2e; QK acc initialized to -16*log2e; P = exp2(acc).
// grid = (64, 16) hw; remapped so each XCD owns 2 consecutive heads (K/V fit its L2).
__global__ __launch_bounds__(256) void k_attn(const unsigned short* __restrict__ qh,
                                              const unsigned short* __restrict__ kh,
                                              const unsigned short* __restrict__ vt,
                                              unsigned short* __restrict__ y) {
  const int bid = blockIdx.x + (blockIdx.y << 6);
  const int logical = (bid & 7) * 128 + (bid >> 3);  // bijective: 1024 = 8 XCD x 128
  const int qi = logical & 63;
  const int h = logical >> 6;
  const int kvh = h >> 2;
  const int tid = threadIdx.x;
  const int w = tid >> 6, l = tid & 63;
  const int lr = l & 15, lq = l >> 4;
  const int t0 = qi * 128;
  const int qrow0 = t0 + 32 * w;

  __shared__ __align__(16) unsigned short Pl[4][32 * 136];
  unsigned short* pw = &Pl[w][0];

  const unsigned short* qbase = qh + (long)h * 8192 * 128;
  const unsigned short* kbase = kh + (long)kvh * 8192 * 128;
  const unsigned short* vbase = vt + (long)kvh * 128 * 8192;

  bf16x8 aq[2][4];
#pragma unroll
  for (int mi = 0; mi < 2; mi++)
#pragma unroll
    for (int kk = 0; kk < 4; kk++)
      aq[mi][kk] = *(const bf16x8*)(qbase + (long)(qrow0 + 16 * mi + lr) * 128 + 32 * kk + 8 * lq);

  f32x4 o[2][8] = {};
  float lsum[2][4] = {};

  const float C0 = -23.08312065f;  // -16 * log2(e): fixed softmax max = 16 (|s|<13.3 provably)
  const int ktlo = (qi >= 8) ? (qi - 8) : 0;
  for (int kt = ktlo; kt <= qi; ++kt) {
    const int key0 = kt * 128;
    const int d = key0 - qrow0;
    if (d <= -1120) continue;  // whole tile outside this wave's window (w=3, kt=qi-8)

    f32x4 s[2][8];
#pragma unroll
    for (int mi = 0; mi < 2; mi++)
#pragma unroll
      for (int ni = 0; ni < 8; ni++)
        s[mi][ni] = f32x4{C0, C0, C0, C0};
#pragma unroll
    for (int kk = 0; kk < 4; kk++) {
#pragma unroll
      for (int ni = 0; ni < 8; ni++) {
        bf16x8 bk = *(const bf16x8*)(kbase + (long)(key0 + 16 * ni + lr) * 128 + 32 * kk + 8 * lq);
        s[0][ni] = mfma_bf16(aq[0][kk], bk, s[0][ni]);
        s[1][ni] = mfma_bf16(aq[1][kk], bk, s[1][ni]);
      }
    }
    // interior tiles (-992 <= d <= -127) are provably fully inside the causal window
    if (d > -127 || d < -992) {
#pragma unroll
      for (int mi = 0; mi < 2; mi++) {
#pragma unroll
        for (int ni = 0; ni < 8; ni++) {
          const int key = key0 + 16 * ni + lr;
#pragma unroll
          for (int r = 0; r < 4; r++) {
            const int trow = qrow0 + 16 * mi + 4 * lq + r;
            bool valid = (key <= trow) && (key + 1024 > trow);
            if (!valid) s[mi][ni][r] = -1e30f;
          }
        }
      }
    }
    // P = exp2(s); per-lane lsum (no cross-lane ops in the loop); store to LDS
#pragma unroll
    for (int mi = 0; mi < 2; mi++)
#pragma unroll
      for (int ni = 0; ni < 8; ni++)
#pragma unroll
        for (int r = 0; r < 4; r++) {
          float p = exp2f(s[mi][ni][r]);
          lsum[mi][r] += p;
          pw[(16 * mi + 4 * lq + r) * 136 + 16 * ni + lr] = f2bf(p);
        }
#pragma unroll
    for (int ks = 0; ks < 4; ks++) {
      bf16x8 pa0 = *(const bf16x8*)(pw + lr * 136 + 32 * ks + 8 * lq);
      bf16x8 pa1 = *(const bf16x8*)(pw + (16 + lr) * 136 + 32 * ks + 8 * lq);
#pragma unroll
      for (int ni = 0; ni < 8; ni++) {
        bf16x8 vb = *(const bf16x8*)(vbase + (long)(16 * ni + lr) * 8192 + key0 + 32 * ks + 8 * lq);
        o[0][ni] = mfma_bf16(pa0, vb, o[0][ni]);
        o[1][ni] = mfma_bf16(pa1, vb, o[1][ni]);
      }
    }
  }
  // epilogue: single cross-lane reduce of lsum (lanes sharing lq), divide, store
#pragma unroll
  for (int mi = 0; mi < 2; mi++) {
#pragma unroll
    for (int r = 0; r < 4; r++) {
      float tot = lsum[mi][r];
      tot += __shfl_xor(tot, 1);
      tot += __shfl_xor(tot, 2);
      tot += __shfl_xor(tot, 4);
      tot += __shfl_xor(tot, 8);
      float inv = 1.0f / tot;
      const long trow = qrow0 + 16 * mi + 4 * lq + r;
#pragma unroll
      for (int ni = 0; ni < 8; ni++)
        y[trow * 2048 + h * 128 + 16 * ni + lr] = f2bf(o[mi][ni][r] * inv);
    }
  }
}

extern "C" void kernel_launch(void* const* d_in, const int* in_sizes, int n_in,
                              void* d_out, int out_size, void* d_ws, size_t ws_size,
                              hipStream_t stream) {
  const float* x = (const float*)d_in[0];
  const float* cosp = (const float*)d_in[1];
  const float* sinp = (const float*)d_in[2];
  const float* Wq = (const float*)d_in[3];
  const float* Wk = (const float*)d_in[4];
  const float* Wv = (const float*)d_in[5];
  const float* Wp = (const float*)d_in[6];
  float* out = (float*)d_out;
  char* ws = (char*)d_ws;

  // workspace (96 MB peak, overlapped lifetimes):
  //  [0,        33.5M)  xb (x bf16)        -> qh after Q-GEMM+pointwise_q
  //  [33.5M,    41.9M)  Wtq (Wq^T bf16)    (dead after Q-GEMM)
  //  [41.9M,    50.3M)  Wkv hi|lo          -> kh after KV-GEMM
  //  [50.3M,    58.7M)  Wpt (Wproj^T)      (live to end)
  //  [58.7M,    92.3M)  kv f32             -> qkv_q bf16 -> y bf16
  //  [92.3M,   100.7M)  vt
  unsigned short* xb    = (unsigned short*)(ws);
  unsigned short* Wtq   = (unsigned short*)(ws + 33554432L);
  unsigned short* Wkh   = (unsigned short*)(ws + 41943040L);
  unsigned short* Wkl   = (unsigned short*)(ws + 46137344L);
  unsigned short* Wpt   = (unsigned short*)(ws + 50331648L);
  float*          kv    = (float*)(ws + 58720256L);
  unsigned short* vt    = (unsigned short*)(ws + 92274688L);
  unsigned short* qh    = xb;                                   // over xb
  unsigned short* kh    = (unsigned short*)(ws + 41943040L);    // over Wkh+Wkl
  unsigned short* qkv_q = (unsigned short*)(ws + 58720256L);    // over kv
  unsigned short* y     = qkv_q;                                // over qkv_q

  dim3 tb(32, 8);
  k_cvt_bf16<<<16384, 256, 0, stream>>>(x, xb, 4194304);
  k_transpose_cvt<<<dim3(64, 64), tb, 0, stream>>>(Wq, Wtq, 2048, 2048);
  k_transpose_cvt<<<dim3(64, 64), tb, 0, stream>>>(Wp, Wpt, 2048, 2048);
  k_transpose_split<<<dim3(16, 64), tb, 0, stream>>>(Wk, Wkh, Wkl, 2048, 512);
  k_transpose_split<<<dim3(16, 64), tb, 0, stream>>>(Wv, Wkh + 512L * 2048L, Wkl + 512L * 2048L, 2048, 512);

  k_gemm_kv<<<dim3(64, 8), 256, 0, stream>>>(x, Wkh, Wkl, kv, 8192, 1024, 2048);
  k_pointwise_kv<<<16384, 256, 0, stream>>>(kv, cosp, sinp, kh, vt);
  k_gemm_bt<0><<<dim3(64, 16), 256, 0, stream>>>(xb, Wtq, (void*)qkv_q, 8192, 2048, 2048);
  k_pointwise_q<<<32768, 256, 0, stream>>>(qkv_q, cosp, sinp, qh);
  k_attn<<<dim3(64, 16), 256, 0, stream>>>(qh, kh, vt, y);
  k_gemm_bt<1><<<dim3(64, 16), 256, 0, stream>>>(y, Wpt, (void*)out, 8192, 2048, 2048);
}